// Round 1
// baseline (2958.734 us; speedup 1.0000x reference)
//
#include <hip/hip_runtime.h>
#include <math.h>

#define HD 64
#define FIN 512
#define NC 40
#define PCH 128
#define PNV 8

struct __align__(8) EdgeT { int s; float v; };

// ---------------- graph preprocessing ----------------

__global__ __launch_bounds__(256) void init_kernel(float* deg, int* counts, int n) {
    int i = blockIdx.x * 256 + threadIdx.x;
    if (i < n) { deg[i] = 1.0f; counts[i] = 0; }   // self-loop weight 1
}

__global__ __launch_bounds__(256) void hist_kernel(const int* __restrict__ dst,
        const float* __restrict__ w, float* deg, int* counts, int E) {
    int i = blockIdx.x * 256 + threadIdx.x;
    if (i < E) {
        int d = dst[i];
        atomicAdd(&deg[d], w[i]);
        atomicAdd(&counts[d], 1);
    }
}

__global__ __launch_bounds__(256) void dinv_kernel(const float* __restrict__ deg,
        float* __restrict__ dinv, int n) {
    int i = blockIdx.x * 256 + threadIdx.x;
    if (i < n) { float d = deg[i]; dinv[i] = d > 0.f ? rsqrtf(d) : 0.f; }
}

__global__ __launch_bounds__(256) void scan_block_kernel(const int* __restrict__ counts,
        int* __restrict__ row_ptr, int* __restrict__ bsums, int n) {
    __shared__ int s[256];
    int t = threadIdx.x;
    int i = blockIdx.x * 256 + t;
    int v = (i < n) ? counts[i] : 0;
    s[t] = v; __syncthreads();
    for (int off = 1; off < 256; off <<= 1) {
        int u = (t >= off) ? s[t - off] : 0;
        __syncthreads();
        s[t] += u;
        __syncthreads();
    }
    if (i < n) row_ptr[i] = s[t] - v;          // exclusive within block
    if (t == 255) bsums[blockIdx.x] = s[255];  // block total
}

__global__ __launch_bounds__(512) void scan_top_kernel(int* bsums, int nb) {
    __shared__ int s[512];
    int t = threadIdx.x;
    int v = (t < nb) ? bsums[t] : 0;
    s[t] = v; __syncthreads();
    for (int off = 1; off < 512; off <<= 1) {
        int u = (t >= off) ? s[t - off] : 0;
        __syncthreads();
        s[t] += u;
        __syncthreads();
    }
    if (t < nb) bsums[t] = s[t] - v;           // exclusive
}

__global__ __launch_bounds__(256) void scan_add_kernel(int* __restrict__ row_ptr,
        const int* __restrict__ bsums, int* __restrict__ cursor, int n, int E) {
    int i = blockIdx.x * 256 + threadIdx.x;
    if (i < n) {
        int v = row_ptr[i] + bsums[blockIdx.x];
        row_ptr[i] = v;
        cursor[i] = v;
    }
    if (i == 0) row_ptr[n] = E;
}

__global__ __launch_bounds__(256) void scatter_kernel(const int* __restrict__ src,
        const int* __restrict__ dst, const float* __restrict__ w,
        const float* __restrict__ dinv, int* __restrict__ cursor,
        EdgeT* __restrict__ ed, int E) {
    int i = blockIdx.x * 256 + threadIdx.x;
    if (i < E) {
        int s = src[i], d = dst[i];
        int pos = atomicAdd(&cursor[d], 1);
        EdgeT e; e.s = s; e.v = dinv[s] * w[i] * dinv[d];
        ed[pos] = e;
    }
}

// ---------------- input projection: h0 = relu(x @ W_in + b_in) ----------------

__global__ __launch_bounds__(256) void proj_kernel(const float* __restrict__ x,
        const float* __restrict__ Wp, const float* __restrict__ bp,
        float* __restrict__ h0, int n) {
    __shared__ float Wl[PCH * HD];     // 32 KB
    const int lane = threadIdx.x & 63;
    int wid = (blockIdx.x << 2) | (threadIdx.x >> 6);
    int node0 = __builtin_amdgcn_readfirstlane(wid * PNV);

    const float* xr[PNV];
#pragma unroll
    for (int v = 0; v < PNV; ++v) {
        int node = node0 + v; if (node >= n) node = n - 1;
        xr[v] = x + (size_t)node * FIN;
    }
    float acc[PNV];
    float bv = bp[lane];
#pragma unroll
    for (int v = 0; v < PNV; ++v) acc[v] = bv;

    for (int c = 0; c < FIN; c += PCH) {
        __syncthreads();
        for (int i = threadIdx.x; i < PCH * HD; i += 256) Wl[i] = Wp[c * HD + i];
        __syncthreads();
#pragma unroll 4
        for (int j = 0; j < PCH; ++j) {
            float w = Wl[j * HD + lane];
#pragma unroll
            for (int v = 0; v < PNV; ++v) {
                acc[v] = fmaf(xr[v][c + j], w, acc[v]);  // wave-uniform x read
            }
        }
    }
#pragma unroll
    for (int v = 0; v < PNV; ++v) {
        int node = node0 + v;
        if (node < n) h0[(size_t)node * HD + lane] = fmaxf(acc[v], 0.f);
    }
}

// ---------------- fused layer: SpMM + residual + 64x64 GEMM + relu ----------------

__global__ __launch_bounds__(256) void layer_kernel(const float* __restrict__ h_in,
        const float* __restrict__ h0, float* __restrict__ h_out,
        const float* __restrict__ W, const float* __restrict__ dinv,
        const int* __restrict__ row_ptr, const EdgeT* __restrict__ ed,
        float beta, int n) {
    __shared__ float Wl[HD * HD];      // 16 KB
    for (int i = threadIdx.x; i < HD * HD; i += 256) Wl[i] = W[i];
    __syncthreads();
    const int lane = threadIdx.x & 63;
    int wid = (blockIdx.x * 256 + threadIdx.x) >> 6;
    int nw = (gridDim.x * 256) >> 6;
    const float ombeta = 1.f - beta;
    for (int node = wid; node < n; node += nw) {
        float di = dinv[node];
        float acc = di * di * h_in[(size_t)node * HD + lane];   // self-loop
        int beg = row_ptr[node], end = row_ptr[node + 1];
        for (int e = beg; e < end; ++e) {
            EdgeT E0 = ed[e];                                   // 8B broadcast load
            acc = fmaf(E0.v, h_in[(size_t)E0.s * HD + lane], acc);
        }
        float sup = fmaf(0.9f, acc, 0.1f * h0[(size_t)node * HD + lane]);
        float g = 0.f;
#pragma unroll
        for (int j = 0; j < HD; ++j) {
            float b = __shfl(sup, j, 64);
            g = fmaf(b, Wl[j * HD + lane], g);
        }
        h_out[(size_t)node * HD + lane] = fmaxf(fmaf(beta, g, ombeta * sup), 0.f);
    }
}

// ---------------- output: log_softmax(h @ W_out + b_out) ----------------

__global__ __launch_bounds__(256) void out_kernel(const float* __restrict__ h,
        const float* __restrict__ Wo, const float* __restrict__ bo,
        float* __restrict__ out, int n) {
    __shared__ float Wl[HD * HD];      // zero-padded to 64 cols, 16 KB
    __shared__ float bl[HD];
    for (int i = threadIdx.x; i < HD * HD; i += 256) {
        int k = i >> 6, c = i & 63;
        Wl[i] = (c < NC) ? Wo[k * NC + c] : 0.f;
    }
    if (threadIdx.x < HD) bl[threadIdx.x] = (threadIdx.x < NC) ? bo[threadIdx.x] : 0.f;
    __syncthreads();
    const int lane = threadIdx.x & 63;
    int wid = (blockIdx.x * 256 + threadIdx.x) >> 6;
    int nw = (gridDim.x * 256) >> 6;
    for (int node = wid; node < n; node += nw) {
        float hv = h[(size_t)node * HD + lane];
        float o = bl[lane];
#pragma unroll
        for (int k = 0; k < HD; ++k) {
            float b = __shfl(hv, k, 64);
            o = fmaf(b, Wl[k * HD + lane], o);
        }
        float m = (lane < NC) ? o : -3.0e38f;
#pragma unroll
        for (int off = 32; off >= 1; off >>= 1) m = fmaxf(m, __shfl_xor(m, off, 64));
        float e = (lane < NC) ? __expf(o - m) : 0.f;
        float ssum = e;
#pragma unroll
        for (int off = 32; off >= 1; off >>= 1) ssum += __shfl_xor(ssum, off, 64);
        float lse = __logf(ssum);
        if (lane < NC) out[(size_t)node * NC + lane] = o - m - lse;
    }
}

// ---------------- launch ----------------

extern "C" void kernel_launch(void* const* d_in, const int* in_sizes, int n_in,
                              void* d_out, int out_size, void* d_ws, size_t ws_size,
                              hipStream_t stream) {
    const float* x        = (const float*)d_in[0];
    const int*   eidx     = (const int*)d_in[1];
    const float* ew       = (const float*)d_in[2];
    const float* W_in     = (const float*)d_in[3];
    const float* b_in     = (const float*)d_in[4];
    const float* W_layers = (const float*)d_in[5];
    const float* W_out    = (const float*)d_in[6];
    const float* b_out    = (const float*)d_in[7];
    float* out = (float*)d_out;

    const int N = in_sizes[0] / FIN;
    const int E = in_sizes[2];
    const int L = in_sizes[5] / (HD * HD);
    const int* src = eidx;
    const int* dst = eidx + E;

    // workspace carve-up (256B aligned)
    size_t off = 0;
    auto carve = [&](size_t bytes) {
        void* p = (char*)d_ws + off;
        off += (bytes + 255) & ~(size_t)255;
        return p;
    };
    float* deg     = (float*)carve((size_t)N * 4);
    float* dinv    = (float*)carve((size_t)N * 4);
    int*   counts  = (int*)  carve((size_t)N * 4);
    int*   cursor  = (int*)  carve((size_t)N * 4);
    int*   row_ptr = (int*)  carve((size_t)(N + 1) * 4);
    int*   bsums   = (int*)  carve(512 * 4);
    EdgeT* ed      = (EdgeT*)carve((size_t)E * 8);
    float* h0      = (float*)carve((size_t)N * HD * 4);
    float* hA      = (float*)carve((size_t)N * HD * 4);
    float* hB      = (float*)carve((size_t)N * HD * 4);
    (void)ws_size;

    const int NB  = (N + 255) / 256;
    const int EB  = (E + 255) / 256;

    init_kernel<<<NB, 256, 0, stream>>>(deg, counts, N);
    hist_kernel<<<EB, 256, 0, stream>>>(dst, ew, deg, counts, E);
    dinv_kernel<<<NB, 256, 0, stream>>>(deg, dinv, N);
    scan_block_kernel<<<NB, 256, 0, stream>>>(counts, row_ptr, bsums, N);
    scan_top_kernel<<<1, 512, 0, stream>>>(bsums, NB);
    scan_add_kernel<<<NB, 256, 0, stream>>>(row_ptr, bsums, cursor, N, E);
    scatter_kernel<<<EB, 256, 0, stream>>>(src, dst, ew, dinv, cursor, ed, E);

    int pblocks = (N + PNV * 4 - 1) / (PNV * 4);
    proj_kernel<<<pblocks, 256, 0, stream>>>(x, W_in, b_in, h0, N);

    const float* cur = h0;
    float* pp[2] = { hA, hB };
    for (int i = 0; i < L; ++i) {
        float beta = logf(0.5f / (float)(i + 1) + 1.0f);
        float* nxt = pp[i & 1];
        layer_kernel<<<2048, 256, 0, stream>>>(cur, h0, nxt, W_layers + (size_t)i * HD * HD,
                                               dinv, row_ptr, ed, beta, N);
        cur = nxt;
    }

    out_kernel<<<2048, 256, 0, stream>>>(cur, W_out, b_out, out, N);
}

// Round 2
// 807.767 us; speedup vs baseline: 3.6629x; 3.6629x over previous
//
#include <hip/hip_runtime.h>
#include <math.h>

#define HD 64
#define FIN 512
#define NC 40

struct __align__(8) EdgeT { int s; float v; };

// ---------------- graph preprocessing ----------------

__global__ __launch_bounds__(256) void init_kernel(float* deg, int* counts, int n) {
    int i = blockIdx.x * 256 + threadIdx.x;
    if (i < n) { deg[i] = 1.0f; counts[i] = 0; }   // self-loop weight 1
}

__global__ __launch_bounds__(256) void hist_kernel(const int* __restrict__ dst,
        const float* __restrict__ w, float* deg, int* counts, int E) {
    int i = blockIdx.x * 256 + threadIdx.x;
    if (i < E) {
        int d = dst[i];
        atomicAdd(&deg[d], w[i]);
        atomicAdd(&counts[d], 1);
    }
}

__global__ __launch_bounds__(256) void dinv_kernel(const float* __restrict__ deg,
        float* __restrict__ dinv, int n) {
    int i = blockIdx.x * 256 + threadIdx.x;
    if (i < n) { float d = deg[i]; dinv[i] = d > 0.f ? rsqrtf(d) : 0.f; }
}

__global__ __launch_bounds__(256) void scan_block_kernel(const int* __restrict__ counts,
        int* __restrict__ row_ptr, int* __restrict__ bsums, int n) {
    __shared__ int s[256];
    int t = threadIdx.x;
    int i = blockIdx.x * 256 + t;
    int v = (i < n) ? counts[i] : 0;
    s[t] = v; __syncthreads();
    for (int off = 1; off < 256; off <<= 1) {
        int u = (t >= off) ? s[t - off] : 0;
        __syncthreads();
        s[t] += u;
        __syncthreads();
    }
    if (i < n) row_ptr[i] = s[t] - v;
    if (t == 255) bsums[blockIdx.x] = s[255];
}

__global__ __launch_bounds__(512) void scan_top_kernel(int* bsums, int nb) {
    __shared__ int s[512];
    int t = threadIdx.x;
    int v = (t < nb) ? bsums[t] : 0;
    s[t] = v; __syncthreads();
    for (int off = 1; off < 512; off <<= 1) {
        int u = (t >= off) ? s[t - off] : 0;
        __syncthreads();
        s[t] += u;
        __syncthreads();
    }
    if (t < nb) bsums[t] = s[t] - v;
}

__global__ __launch_bounds__(256) void scan_add_kernel(int* __restrict__ row_ptr,
        const int* __restrict__ bsums, int* __restrict__ cursor, int n, int E) {
    int i = blockIdx.x * 256 + threadIdx.x;
    if (i < n) {
        int v = row_ptr[i] + bsums[blockIdx.x];
        row_ptr[i] = v;
        cursor[i] = v;
    }
    if (i == 0) row_ptr[n] = E;
}

__global__ __launch_bounds__(256) void scatter_kernel(const int* __restrict__ src,
        const int* __restrict__ dst, const float* __restrict__ w,
        const float* __restrict__ dinv, int* __restrict__ cursor,
        EdgeT* __restrict__ ed, int E) {
    int i = blockIdx.x * 256 + threadIdx.x;
    if (i < E) {
        int s = src[i], d = dst[i];
        int pos = atomicAdd(&cursor[d], 1);
        EdgeT e; e.s = s; e.v = dinv[s] * w[i] * dinv[d];
        ed[pos] = e;
    }
}

__global__ __launch_bounds__(256) void pad_kernel(const float* __restrict__ Wo,
        const float* __restrict__ bo, float* __restrict__ Wo_pad,
        float* __restrict__ bo_pad) {
    int i = blockIdx.x * 256 + threadIdx.x;
    if (i < HD * HD) {
        int k = i >> 6, c = i & 63;
        Wo_pad[i] = (c < NC) ? Wo[k * NC + c] : 0.f;
    }
    if (i < HD) bo_pad[i] = (i < NC) ? bo[i] : 0.f;
}

// ---------------- SpMM: sup = 0.9*(Ahat @ h_in) + 0.1*h0 ----------------

__global__ __launch_bounds__(256) void spmm_kernel(const float* __restrict__ h_in,
        const float* __restrict__ h0, float* __restrict__ sup,
        const float* __restrict__ dinv, const int* __restrict__ row_ptr,
        const EdgeT* __restrict__ ed, int n) {
    const int lane = threadIdx.x & 63;
    int wid = (blockIdx.x * 256 + threadIdx.x) >> 6;
    int nw = (gridDim.x * 256) >> 6;
    for (int node = wid; node < n; node += nw) {
        float di = dinv[node];
        float a0 = di * di * h_in[(size_t)node * HD + lane];
        float a1 = 0.f, a2 = 0.f, a3 = 0.f;
        int e = row_ptr[node], end = row_ptr[node + 1];
        for (; e + 4 <= end; e += 4) {
            EdgeT E0 = ed[e], E1 = ed[e + 1], E2 = ed[e + 2], E3 = ed[e + 3];
            a0 = fmaf(E0.v, h_in[(size_t)E0.s * HD + lane], a0);
            a1 = fmaf(E1.v, h_in[(size_t)E1.s * HD + lane], a1);
            a2 = fmaf(E2.v, h_in[(size_t)E2.s * HD + lane], a2);
            a3 = fmaf(E3.v, h_in[(size_t)E3.s * HD + lane], a3);
        }
        for (; e < end; ++e) {
            EdgeT E0 = ed[e];
            a0 = fmaf(E0.v, h_in[(size_t)E0.s * HD + lane], a0);
        }
        float acc = (a0 + a1) + (a2 + a3);
        sup[(size_t)node * HD + lane] = fmaf(0.9f, acc, 0.1f * h0[(size_t)node * HD + lane]);
    }
}

// ---------------- tiled GEMM: C[n][64] = epilogue(A[n][K] @ W[K][64]) ----------------
// MODE 0: relu(acc + bias)                -> C
// MODE 1: relu(beta*acc + (1-beta)*A)     -> C (in-place over A is safe)
// MODE 2: log_softmax(acc + bias) over first NC cols -> outp [n][NC]

template<int MODE>
__global__ __launch_bounds__(256) void gemm64_kernel(
        const float* __restrict__ A, const float* __restrict__ W,
        const float* __restrict__ bias, float* __restrict__ C,
        int n, int K, float beta, float* __restrict__ outp) {
    __shared__ float Alds[256 * 64];   // 64 KB, rows XOR-swizzled
    __shared__ float Wlds[64 * 64];    // 16 KB
    const int tid = threadIdx.x;
    const int tx = tid & 7;            // out-group: outs [tx*8, tx*8+8)
    const int ty = tid >> 3;           // node-group: nodes [ty*8, ty*8+8)
    const int base = blockIdx.x * 256;

    float acc[8][8];
#pragma unroll
    for (int i = 0; i < 8; ++i)
#pragma unroll
        for (int j = 0; j < 8; ++j) acc[i][j] = 0.f;

    const int k0 = (tid & 15) * 4;
    const int rq = tid >> 4;           // [0,16)

    for (int kc = 0; kc < K; kc += 64) {
        __syncthreads();
        // stage A chunk [256 nodes][64 k], swizzled
#pragma unroll
        for (int p = 0; p < 16; ++p) {
            int nloc = rq + p * 16;
            int ng = base + nloc; if (ng >= n) ng = n - 1;
            float4 v = *(const float4*)(A + (size_t)ng * K + kc + k0);
            int swz = ((nloc >> 3) & 7) << 2;
            *(float4*)(Alds + nloc * 64 + (k0 ^ swz)) = v;
        }
        // stage W chunk [64][64]
#pragma unroll
        for (int p = 0; p < 4; ++p) {
            int kr = rq + p * 16;
            *(float4*)(Wlds + kr * 64 + k0) =
                *(const float4*)(W + (size_t)(kc + kr) * HD + k0);
        }
        __syncthreads();

        const int swz = (ty & 7) << 2;
#pragma unroll
        for (int kk = 0; kk < 64; kk += 4) {
            float a[8][4];
#pragma unroll
            for (int i = 0; i < 8; ++i) {
                float4 v = *(const float4*)(Alds + (ty * 8 + i) * 64 + (kk ^ swz));
                a[i][0] = v.x; a[i][1] = v.y; a[i][2] = v.z; a[i][3] = v.w;
            }
#pragma unroll
            for (int k2 = 0; k2 < 4; ++k2) {
                float w[8];
                *(float4*)&w[0] = *(const float4*)(Wlds + (kk + k2) * 64 + tx * 8);
                *(float4*)&w[4] = *(const float4*)(Wlds + (kk + k2) * 64 + tx * 8 + 4);
#pragma unroll
                for (int i = 0; i < 8; ++i)
#pragma unroll
                    for (int j = 0; j < 8; ++j)
                        acc[i][j] = fmaf(a[i][k2], w[j], acc[i][j]);
            }
        }
    }

    // ---- epilogue ----
    if constexpr (MODE == 0) {
        float b[8];
#pragma unroll
        for (int j = 0; j < 8; ++j) b[j] = bias[tx * 8 + j];
#pragma unroll
        for (int i = 0; i < 8; ++i) {
            int ng = base + ty * 8 + i;
            if (ng < n) {
                float r[8];
#pragma unroll
                for (int j = 0; j < 8; ++j) r[j] = fmaxf(acc[i][j] + b[j], 0.f);
                *(float4*)(C + (size_t)ng * HD + tx * 8)     = *(float4*)&r[0];
                *(float4*)(C + (size_t)ng * HD + tx * 8 + 4) = *(float4*)&r[4];
            }
        }
    } else if constexpr (MODE == 1) {
        const float ombeta = 1.f - beta;
        const int swz = (ty & 7) << 2;
#pragma unroll
        for (int i = 0; i < 8; ++i) {
            int nloc = ty * 8 + i;
            int ng = base + nloc;
            float r[8];
#pragma unroll
            for (int j = 0; j < 8; ++j) {
                float sup = Alds[nloc * 64 + ((tx * 8 + j) ^ swz)];
                r[j] = fmaxf(fmaf(beta, acc[i][j], ombeta * sup), 0.f);
            }
            if (ng < n) {
                *(float4*)(C + (size_t)ng * HD + tx * 8)     = *(float4*)&r[0];
                *(float4*)(C + (size_t)ng * HD + tx * 8 + 4) = *(float4*)&r[4];
            }
        }
    } else {
        float b[8];
#pragma unroll
        for (int j = 0; j < 8; ++j) b[j] = bias[tx * 8 + j];
#pragma unroll
        for (int i = 0; i < 8; ++i) {
            float lo[8];
            float m = -3.0e38f;
#pragma unroll
            for (int j = 0; j < 8; ++j) {
                int o = tx * 8 + j;
                float v = acc[i][j] + b[j];
                lo[j] = v;
                if (o < NC) m = fmaxf(m, v);
            }
            m = fmaxf(m, __shfl_xor(m, 1, 64));
            m = fmaxf(m, __shfl_xor(m, 2, 64));
            m = fmaxf(m, __shfl_xor(m, 4, 64));
            float s = 0.f;
#pragma unroll
            for (int j = 0; j < 8; ++j) {
                int o = tx * 8 + j;
                if (o < NC) s += __expf(lo[j] - m);
            }
            s += __shfl_xor(s, 1, 64);
            s += __shfl_xor(s, 2, 64);
            s += __shfl_xor(s, 4, 64);
            float lse = __logf(s);
            int ng = base + ty * 8 + i;
            if (ng < n) {
#pragma unroll
                for (int j = 0; j < 8; ++j) {
                    int o = tx * 8 + j;
                    if (o < NC) outp[(size_t)ng * NC + o] = lo[j] - m - lse;
                }
            }
        }
    }
}

// ---------------- launch ----------------

extern "C" void kernel_launch(void* const* d_in, const int* in_sizes, int n_in,
                              void* d_out, int out_size, void* d_ws, size_t ws_size,
                              hipStream_t stream) {
    const float* x        = (const float*)d_in[0];
    const int*   eidx     = (const int*)d_in[1];
    const float* ew       = (const float*)d_in[2];
    const float* W_in     = (const float*)d_in[3];
    const float* b_in     = (const float*)d_in[4];
    const float* W_layers = (const float*)d_in[5];
    const float* W_out    = (const float*)d_in[6];
    const float* b_out    = (const float*)d_in[7];
    float* out = (float*)d_out;

    const int N = in_sizes[0] / FIN;
    const int E = in_sizes[2];
    const int L = in_sizes[5] / (HD * HD);
    const int* src = eidx;
    const int* dst = eidx + E;

    size_t off = 0;
    auto carve = [&](size_t bytes) {
        void* p = (char*)d_ws + off;
        off += (bytes + 255) & ~(size_t)255;
        return p;
    };
    float* deg     = (float*)carve((size_t)N * 4);
    float* dinv    = (float*)carve((size_t)N * 4);
    int*   counts  = (int*)  carve((size_t)N * 4);
    int*   cursor  = (int*)  carve((size_t)N * 4);
    int*   row_ptr = (int*)  carve((size_t)(N + 1) * 4);
    int*   bsums   = (int*)  carve(512 * 4);
    float* Wo_pad  = (float*)carve((size_t)HD * HD * 4);
    float* bo_pad  = (float*)carve((size_t)HD * 4);
    EdgeT* ed      = (EdgeT*)carve((size_t)E * 8);
    float* h0      = (float*)carve((size_t)N * HD * 4);
    float* hA      = (float*)carve((size_t)N * HD * 4);
    float* hB      = (float*)carve((size_t)N * HD * 4);
    (void)ws_size;

    const int NB = (N + 255) / 256;
    const int EB = (E + 255) / 256;

    init_kernel<<<NB, 256, 0, stream>>>(deg, counts, N);
    hist_kernel<<<EB, 256, 0, stream>>>(dst, ew, deg, counts, E);
    dinv_kernel<<<NB, 256, 0, stream>>>(deg, dinv, N);
    scan_block_kernel<<<NB, 256, 0, stream>>>(counts, row_ptr, bsums, N);
    scan_top_kernel<<<1, 512, 0, stream>>>(bsums, NB);
    scan_add_kernel<<<NB, 256, 0, stream>>>(row_ptr, bsums, cursor, N, E);
    scatter_kernel<<<EB, 256, 0, stream>>>(src, dst, ew, dinv, cursor, ed, E);
    pad_kernel<<<16, 256, 0, stream>>>(W_out, b_out, Wo_pad, bo_pad);

    const int NGB = (N + 255) / 256;   // gemm tile blocks

    // input projection
    gemm64_kernel<0><<<NGB, 256, 0, stream>>>(x, W_in, b_in, h0, N, FIN, 0.f, nullptr);

    const float* cur = h0;
    float* bufs[2] = { hA, hB };
    for (int i = 0; i < L; ++i) {
        float beta = logf(0.5f / (float)(i + 1) + 1.0f);
        float* sup = bufs[i & 1];
        spmm_kernel<<<2048, 256, 0, stream>>>(cur, h0, sup, dinv, row_ptr, ed, N);
        gemm64_kernel<1><<<NGB, 256, 0, stream>>>(sup, W_layers + (size_t)i * HD * HD,
                                                  nullptr, sup, N, HD, beta, nullptr);
        cur = sup;
    }

    // output projection + fused log_softmax
    gemm64_kernel<2><<<NGB, 256, 0, stream>>>(cur, Wo_pad, bo_pad, nullptr, N, HD, 0.f, out);
}